// Round 1
// baseline (274.936 us; speedup 1.0000x reference)
//
#include <hip/hip_runtime.h>

#define HW 32768      // H*W per batch = 128*256
#define WIDTH 256

typedef float f32x4 __attribute__((ext_vector_type(4)));
typedef short s16x8 __attribute__((ext_vector_type(8)));

__device__ __forceinline__ unsigned short f2bf(float f){
    unsigned int u = __float_as_uint(f);
    u += 0x7FFFu + ((u >> 16) & 1u);      // round-to-nearest-even
    return (unsigned short)(u >> 16);
}
__device__ __forceinline__ unsigned int pk2(float a, float b){
    return (unsigned int)f2bf(a) | ((unsigned int)f2bf(b) << 16);
}

// ---------------------------------------------------------------------------
// k_pre: blocks 0..63 = W1/W2 pre-pack into bf16 MFMA A-fragment layout
//        (pair index pi covers W[F][m*16+l15][kk*32+quad*8+2*j2 .. +1]);
//        block 64 = collapsed geo path:
//        M[s][i][k] = sum_o W_sel[s][i*96+o]*W_geo[o][k];
//        c0[s] = b_sel[s] + sum_{i,o} W_sel[s][i*96+o]*b_geo[o]
// ---------------------------------------------------------------------------
__global__ void k_pre(const float* __restrict__ W1, const float* __restrict__ W2,
                      unsigned int* __restrict__ Wb,
                      const float* __restrict__ Wsel, const float* __restrict__ bsel,
                      const float* __restrict__ Wgeo, const float* __restrict__ bgeo,
                      float* __restrict__ M, float* __restrict__ c0)
{
    if (blockIdx.x < 64){
        const int pi = blockIdx.x * 256 + threadIdx.x;   // 0..16383
        const int j2   = pi & 3;
        const int l15  = (pi >> 2) & 15;
        const int quad = (pi >> 6) & 3;
        const int m    = (pi >> 8) & 7;
        const int kk   = (pi >> 11) & 3;
        const int F    = (pi >> 13) & 1;
        const float* Wm = F ? W2 : W1;
        const int row = m * 16 + l15;
        const int ch  = kk * 32 + quad * 8 + j2 * 2;
        Wb[pi] = pk2(Wm[row * 128 + ch], Wm[row * 128 + ch + 1]);
    } else {
        for (int u = threadIdx.x; u < 444; u += 256){
            if (u < 441){
                int s = u / 147; int r = u % 147; int i = r / 49; int k = r % 49;
                float acc = 0.f;
                for (int o = 0; o < 96; ++o)
                    acc += Wsel[s * 288 + i * 96 + o] * Wgeo[o * 49 + k];
                M[u] = acc;
            } else {
                int s = u - 441;
                float acc = bsel[s];
                for (int i = 0; i < 3; ++i)
                    for (int o = 0; o < 96; ++o)
                        acc += Wsel[s * 288 + i * 96 + o] * bgeo[o];
                c0[s] = acc;
            }
        }
    }
}

// ---------------------------------------------------------------------------
// Fused: fmap GEMMs + per-pixel L2-norm + correlation + geo selection,
// one block per (b,h). Order: f2 GEMM -> f2s(LDS); f1 GEMM -> f1p(regs) ->
// corr -> G(LDS). Epilogue is a dd-loop (thread = pixel): pass 1 streams
// cv0/1/2 once, writes ic as full coalesced 1KB rows and accumulates the 3
// selection logits (same accumulation order as the old k_sel); softmax is
// per-thread (each thread owns a whole pixel); pass 2 re-reads cv (L2-hot),
// recomputes icv from LDS G and writes final + w.
// ---------------------------------------------------------------------------
__global__ __launch_bounds__(256, 2) void k_fused(
    const float* __restrict__ fl, const float* __restrict__ fr,
    const unsigned int* __restrict__ Wbu,
    const float* __restrict__ b1, const float* __restrict__ b2,
    const float* __restrict__ cv0, const float* __restrict__ cv1,
    const float* __restrict__ cv2,
    const float* __restrict__ Mg, const float* __restrict__ c0g,
    float* __restrict__ icO, float* __restrict__ finalO, float* __restrict__ wO)
{
    __shared__ __align__(16) char pool[67584];      // f2s -> G (time-aliased)
    __shared__ float s1[256], s2[256];
    __shared__ float Ms[441];
    __shared__ float c0s[3];
    unsigned short* f2s = (unsigned short*)pool;    // [256 px][132] bf16
    float* G            = (float*)pool;             // [256 rows][66] f32

    const int blk  = blockIdx.x;          // 512 = 4 b x 128 h
    const int b    = blk >> 7;
    const int h    = blk & 127;
    const int tid  = threadIdx.x;
    const int wv   = tid >> 6;
    const int lane = tid & 63;
    const int quad = lane >> 4;
    const int l15  = lane & 15;

    // stage selection matrix early (used only after several barriers)
    for (int i = tid; i < 441; i += 256) Ms[i] = Mg[i];
    if (tid < 3) c0s[tid] = c0g[tid];

    const float* feats[2] = { fl + (size_t)b * 128 * HW + h * WIDTH,
                              fr + (size_t)b * 128 * HW + h * WIDTH };
    const float* bss[2]   = { b1, b2 };

    unsigned int f1p[64];                 // f1 raw bf16 pairs (live only after F=0 GEMM)

    #pragma unroll 1
    for (int Fi = 0; Fi < 2; ++Fi){
        const int F = 1 - Fi;             // f2 first, then f1
        const float* featB = feats[F];
        const float* bias  = bss[F];
        const unsigned int* WbF = Wbu + F * 8192;

        f32x4 acc[8][4];
        #pragma unroll
        for (int m = 0; m < 8; ++m)
            #pragma unroll
            for (int nt = 0; nt < 4; ++nt)
                acc[m][nt] = (f32x4){0.f, 0.f, 0.f, 0.f};

        float buf[3][8];
        // preload tiles 0,1  (tile t = kk*4+nt; px = wv*64 + nt*16 + l15)
        #pragma unroll
        for (int t = 0; t < 2; ++t){
            const float* bp = featB + (size_t)(quad * 8) * HW + wv * 64 + t * 16 + l15;
            #pragma unroll
            for (int j = 0; j < 8; ++j) buf[t][j] = bp[(size_t)j * HW];
        }

        #pragma unroll
        for (int kk = 0; kk < 4; ++kk){
            // A-frags: one 16-B coalesced load per m (pre-packed bf16, L2-hot)
            s16x8 af[8];
            #pragma unroll
            for (int m = 0; m < 8; ++m)
                af[m] = *(const s16x8*)&WbF[(((kk * 8 + m) * 4 + quad) * 16 + l15) * 4];

            #pragma unroll
            for (int nt = 0; nt < 4; ++nt){
                const int t = kk * 4 + nt;
                if (t + 2 < 16){          // issue tile t+2 (2-deep pipeline)
                    const int kk2 = (t + 2) >> 2, nt2 = (t + 2) & 3;
                    const float* bp = featB + (size_t)(kk2 * 32 + quad * 8) * HW
                                      + wv * 64 + nt2 * 16 + l15;
                    #pragma unroll
                    for (int j = 0; j < 8; ++j) buf[(t + 2) % 3][j] = bp[(size_t)j * HW];
                }
                const float* cur = buf[t % 3];
                union { unsigned int u[4]; s16x8 v; } rb;
                rb.u[0] = pk2(cur[0], cur[1]); rb.u[1] = pk2(cur[2], cur[3]);
                rb.u[2] = pk2(cur[4], cur[5]); rb.u[3] = pk2(cur[6], cur[7]);
                #pragma unroll
                for (int m = 0; m < 8; ++m)
                    acc[m][nt] = __builtin_amdgcn_mfma_f32_16x16x32_bf16(af[m], rb.v, acc[m][nt], 0, 0, 0);
            }
        }

        // bias + inverse-norm per pixel
        float inv[4];
        #pragma unroll
        for (int nt = 0; nt < 4; ++nt){
            #pragma unroll
            for (int m = 0; m < 8; ++m)
                acc[m][nt] += *(const f32x4*)(bias + m * 16 + quad * 4);
            float n2 = 0.f;
            #pragma unroll
            for (int m = 0; m < 8; ++m)
                #pragma unroll
                for (int r = 0; r < 4; ++r)
                    n2 += acc[m][nt][r] * acc[m][nt][r];
            n2 += __shfl_xor(n2, 16, 64);
            n2 += __shfl_xor(n2, 32, 64);
            inv[nt] = 1.f / (sqrtf(n2) + 1e-8f);
        }

        if (F == 1){                      // f2 -> LDS (raw bf16) + s2
            if (quad == 0){
                #pragma unroll
                for (int nt = 0; nt < 4; ++nt) s2[wv * 64 + nt * 16 + l15] = inv[nt];
            }
            #pragma unroll
            for (int nt = 0; nt < 4; ++nt){
                const int px = wv * 64 + nt * 16 + l15;
                #pragma unroll
                for (int m = 0; m < 8; ++m){
                    uint2 p;
                    p.x = pk2(acc[m][nt][0], acc[m][nt][1]);
                    p.y = pk2(acc[m][nt][2], acc[m][nt][3]);
                    *(uint2*)&f2s[px * 132 + m * 16 + quad * 4] = p;
                }
            }
        } else {                          // f1 -> registers (raw bf16) + s1
            #pragma unroll
            for (int m = 0; m < 8; ++m)
                #pragma unroll
                for (int nt = 0; nt < 4; ++nt){
                    f1p[m * 8 + nt * 2 + 0] = pk2(acc[m][nt][0], acc[m][nt][1]);
                    f1p[m * 8 + nt * 2 + 1] = pk2(acc[m][nt][2], acc[m][nt][3]);
                }
            if (quad == 0){
                #pragma unroll
                for (int nt = 0; nt < 4; ++nt) s1[wv * 64 + nt * 16 + l15] = inv[nt];
            }
        }
    }
    __syncthreads();                      // f2s complete

    // ---- correlation: per wave 4 strips of 16 px; A from f1p shuffles ----
    f32x4 acc_c[4][4];
    #pragma unroll
    for (int st = 0; st < 4; ++st)
        #pragma unroll
        for (int ct = 0; ct < 4; ++ct)
            acc_c[st][ct] = (f32x4){0.f, 0.f, 0.f, 0.f};

    #pragma unroll
    for (int st = 0; st < 4; ++st){
        s16x8 afc[4];
        #pragma unroll
        for (int kk = 0; kk < 4; ++kk){
            union { unsigned int u[4]; s16x8 v; } r;
            #pragma unroll
            for (int j2 = 0; j2 < 4; ++j2){
                const int rp  = j2 & 1;
                const int qs  = (quad & 1) * 2 + (j2 >> 1);
                const int src = qs * 16 + l15;
                unsigned int a0 = (unsigned int)__shfl((int)f1p[(kk * 2 + 0) * 8 + st * 2 + rp], src, 64);
                unsigned int a1 = (unsigned int)__shfl((int)f1p[(kk * 2 + 1) * 8 + st * 2 + rp], src, 64);
                r.u[j2] = (quad >> 1) ? a1 : a0;
            }
            afc[kk] = r.v;
        }
        #pragma unroll
        for (int ct = 0; ct < 4; ++ct){
            const int s = wv * 64 + st * 16 + ct * 16 + l15 - 24;
            const bool valid = (s >= 0) && (s < WIDTH);
            const int sc = valid ? s : 0;
            #pragma unroll
            for (int kk = 0; kk < 4; ++kk){
                union { uint2 q2[2]; s16x8 v; } rb;
                rb.q2[0] = *(const uint2*)&f2s[sc * 132 + kk * 32 + quad * 8];
                rb.q2[1] = *(const uint2*)&f2s[sc * 132 + kk * 32 + quad * 8 + 4];
                s16x8 bf = rb.v;
                if (!valid) bf = (s16x8){0,0,0,0,0,0,0,0};
                acc_c[st][ct] = __builtin_amdgcn_mfma_f32_16x16x32_bf16(afc[kk], bf, acc_c[st][ct], 0, 0, 0);
            }
        }
    }
    __syncthreads();                      // all f2s reads done; G overwrites pool
    #pragma unroll
    for (int st = 0; st < 4; ++st)
        #pragma unroll
        for (int ct = 0; ct < 4; ++ct)
            #pragma unroll
            for (int r = 0; r < 4; ++r)
                G[((wv * 4 + st) * 16 + quad * 4 + r) * 66 + ct * 16 + l15] = acc_c[st][ct][r];
    __syncthreads();

    // ---- fused epilogue: thread = pixel; dd-loop with full-line writes ----
    // out[dd][px] = G[px][(px&15)+48-dd] * s1[px] * s2[px+24-dd]  (G=0 when OOB)
    const int px = tid;
    const float sc1 = s1[px];
    const float* Gp = &G[px * 66 + (px & 15) + 48];
    const size_t rowoff = (size_t)h * WIDTH + px;
    const size_t cvbase = (size_t)b * 49 * HW + rowoff;
    float* icb = icO    + cvbase;
    float* fnb = finalO + cvbase;
    const float* c0p = cv0 + cvbase;
    const float* c1p = cv1 + cvbase;
    const float* c2p = cv2 + cvbase;

    float lg0 = c0s[0], lg1 = c0s[1], lg2 = c0s[2];
    #pragma unroll 7
    for (int dd = 0; dd < 49; ++dd){
        int s2i = px + 24 - dd;
        s2i = s2i < 0 ? 0 : (s2i > 255 ? 255 : s2i);   // OOB -> G row is 0 anyway
        const float icv = Gp[-dd] * sc1 * s2[s2i];
        icb[(size_t)dd * HW] = icv;
        const float a0 = c0p[(size_t)dd * HW];
        const float a1 = c1p[(size_t)dd * HW];
        const float a2 = c2p[(size_t)dd * HW];
        lg0 += Ms[dd]       * a0 + Ms[49  + dd] * a1 + Ms[98  + dd] * a2;
        lg1 += Ms[147 + dd] * a0 + Ms[196 + dd] * a1 + Ms[245 + dd] * a2;
        lg2 += Ms[294 + dd] * a0 + Ms[343 + dd] * a1 + Ms[392 + dd] * a2;
    }

    const float mx = fmaxf(lg0, fmaxf(lg1, lg2));
    const float e0 = expf(lg0 - mx), e1 = expf(lg1 - mx), e2 = expf(lg2 - mx);
    const float einv = 1.f / (e0 + e1 + e2);
    const float w0 = e0 * einv, w1 = e1 * einv, w2 = e2 * einv;

    float* wb = wO + (size_t)b * 3 * HW + rowoff;
    wb[0]      = w0;
    wb[HW]     = w1;
    wb[2 * HW] = w2;

    #pragma unroll 7
    for (int dd = 0; dd < 49; ++dd){
        int s2i = px + 24 - dd;
        s2i = s2i < 0 ? 0 : (s2i > 255 ? 255 : s2i);
        const float icv = Gp[-dd] * sc1 * s2[s2i];
        fnb[(size_t)dd * HW] = icv + w0 * c0p[(size_t)dd * HW]
                                   + w1 * c1p[(size_t)dd * HW]
                                   + w2 * c2p[(size_t)dd * HW];
    }
}

// ---------------------------------------------------------------------------
extern "C" void kernel_launch(void* const* d_in, const int* in_sizes, int n_in,
                              void* d_out, int out_size, void* d_ws, size_t ws_size,
                              hipStream_t stream)
{
    const float* feat_l1 = (const float*)d_in[0];
    const float* feat_r1 = (const float*)d_in[1];
    const float* cv0     = (const float*)d_in[2];
    const float* cv1     = (const float*)d_in[3];
    const float* cv2     = (const float*)d_in[4];
    const float* W_f1    = (const float*)d_in[5];
    const float* b_f1    = (const float*)d_in[6];
    const float* W_f2    = (const float*)d_in[7];
    const float* b_f2    = (const float*)d_in[8];
    const float* W_geo   = (const float*)d_in[9];
    const float* b_geo   = (const float*)d_in[10];
    const float* W_sel   = (const float*)d_in[11];
    const float* b_sel   = (const float*)d_in[12];

    float* finalO = (float*)d_out;
    float* icO    = (float*)d_out + 6422528;    // 4*49*128*256
    float* wO     = (float*)d_out + 12845056;   // + another 6422528

    unsigned int* Wb = (unsigned int*)d_ws;     // 16384 uints = 64 KB
    float* Mbuf  = (float*)((char*)d_ws + 65536);
    float* c0buf = Mbuf + 441;

    k_pre<<<65, 256, 0, stream>>>(W_f1, W_f2, Wb, W_sel, b_sel, W_geo, b_geo, Mbuf, c0buf);
    k_fused<<<512, 256, 0, stream>>>(feat_l1, feat_r1, Wb, b_f1, b_f2,
                                     cv0, cv1, cv2, Mbuf, c0buf,
                                     icO, finalO, wO);
}